// Round 1
// baseline (547.168 us; speedup 1.0000x reference)
//
#include <hip/hip_runtime.h>

#define B_ 2
#define S_ 2048
#define D_ 1024
#define H_ 16
#define HD_ 64

typedef unsigned short u16;
typedef short bf16x8 __attribute__((ext_vector_type(8)));
typedef float f32x4 __attribute__((ext_vector_type(4)));

union FragU { bf16x8 v; u16 u[8]; uint2 d2[2]; };

__device__ __forceinline__ u16 f2bf(float f) {
  unsigned int x = __builtin_bit_cast(unsigned int, f);
  x += 0x7fffu + ((x >> 16) & 1u);   // round-to-nearest-even
  return (u16)(x >> 16);
}

// ---------------------------------------------------------------------------
// Projection: out[z] = X[z] @ W[z] + b[z]   (z: 0=q, 1=k, 2=v)
// q,k written [B,H,S,64] bf16 (q pre-scaled by 1/8); v written [B,H,64,S] bf16
// Tile: 128 rows x 64 cols (one head), BK=32, 4 waves each 32x64.
// ---------------------------------------------------------------------------
__global__ __launch_bounds__(256) void proj_kernel(
    const float* __restrict__ Xq, const float* __restrict__ Xk, const float* __restrict__ Xv,
    const float* __restrict__ Wq, const float* __restrict__ Wk, const float* __restrict__ Wv,
    const float* __restrict__ bq, const float* __restrict__ bk, const float* __restrict__ bv,
    u16* __restrict__ qo, u16* __restrict__ ko, u16* __restrict__ vo)
{
  const int z = blockIdx.z;
  const float* X  = (z == 0) ? Xq : (z == 1) ? Xk : Xv;
  const float* W  = (z == 0) ? Wq : (z == 1) ? Wk : Wv;
  const float* Bb = (z == 0) ? bq : (z == 1) ? bk : bv;
  u16* out = (z == 0) ? qo : (z == 1) ? ko : vo;
  const float scale = (z == 0) ? 0.125f : 1.0f;   // 1/sqrt(64) folded into q

  const int h = blockIdx.y;
  const int bx = blockIdx.x;
  const int tid = threadIdx.x;
  const int l = tid & 63, w = tid >> 6;
  const int g = l >> 4, lr = l & 15;

  __shared__ u16 Asm[128][36];   // X tile, rows padded to 36 (72B stride: conflict-free)
  __shared__ u16 Wsm[64][36];    // W^T tile [n][k]

  const f32x4 zero = {0.f, 0.f, 0.f, 0.f};
  f32x4 acc[2][4];
  for (int mt = 0; mt < 2; ++mt)
    for (int nt = 0; nt < 4; ++nt) acc[mt][nt] = zero;

  for (int k0 = 0; k0 < D_; k0 += 32) {
    // stage A: 128x32 f32 -> bf16  (coalesced along k)
    #pragma unroll
    for (int i = 0; i < 16; ++i) {
      int idx = tid + i * 256;
      int r = idx >> 5, kk = idx & 31;
      Asm[r][kk] = f2bf(X[(size_t)(bx * 128 + r) * D_ + k0 + kk]);
    }
    // stage W^T: [n][k] (coalesced read along n)
    #pragma unroll
    for (int i = 0; i < 8; ++i) {
      int idx = tid + i * 256;
      int n = idx & 63, kk = idx >> 6;
      Wsm[n][kk] = f2bf(W[((size_t)h * D_ + k0 + kk) * HD_ + n]);
    }
    __syncthreads();

    FragU aF[2], bF[4];
    #pragma unroll
    for (int mt = 0; mt < 2; ++mt) {
      const u16* p = &Asm[w * 32 + mt * 16 + lr][g * 4];
      aF[mt].d2[0] = *(const uint2*)p;
      aF[mt].d2[1] = *(const uint2*)(p + 16);
    }
    #pragma unroll
    for (int nt = 0; nt < 4; ++nt) {
      const u16* p = &Wsm[nt * 16 + lr][g * 4];
      bF[nt].d2[0] = *(const uint2*)p;
      bF[nt].d2[1] = *(const uint2*)(p + 16);
    }
    #pragma unroll
    for (int mt = 0; mt < 2; ++mt)
      #pragma unroll
      for (int nt = 0; nt < 4; ++nt)
        acc[mt][nt] = __builtin_amdgcn_mfma_f32_16x16x32_bf16(aF[mt].v, bF[nt].v, acc[mt][nt], 0, 0, 0);
    __syncthreads();
  }

  // epilogue: + bias, scale, scatter to [B,H,S,64] (or [B,H,64,S] for v)
  #pragma unroll
  for (int nt = 0; nt < 4; ++nt) {
    int n = nt * 16 + lr;
    float bias = Bb[h * HD_ + n];
    #pragma unroll
    for (int mt = 0; mt < 2; ++mt) {
      #pragma unroll
      for (int r = 0; r < 4; ++r) {
        int R = bx * 128 + w * 32 + mt * 16 + g * 4 + r;
        int b = R >> 11, s = R & (S_ - 1);
        float val = (acc[mt][nt][r] + bias) * scale;
        if (z < 2)
          out[(((size_t)b * H_ + h) * S_ + s) * HD_ + n] = f2bf(val);
        else
          out[(((size_t)b * H_ + h) * HD_ + n) * S_ + s] = f2bf(val);
      }
    }
  }
}

// ---------------------------------------------------------------------------
// Flash attention: per block (q-tile 64, bh); 4 waves, each owns 16 q rows.
// KV tiles of 64; online softmax wave-parallel over 16-lane column groups.
// Writes attended (already /l) to [B,S,1024] f32.
// ---------------------------------------------------------------------------
__global__ __launch_bounds__(256) void attn_kernel(
    const u16* __restrict__ q, const u16* __restrict__ k,
    const u16* __restrict__ vt, float* __restrict__ att)
{
  const int bh = blockIdx.y;     // b*16 + h
  const int qt = blockIdx.x;     // q tile of 64
  const int tid = threadIdx.x;
  const int l = tid & 63, w = tid >> 6;
  const int g = l >> 4, lr = l & 15;
  const int qbase = qt * 64 + w * 16;

  __shared__ u16 Plds[4][16][72];   // per-wave P tile, stride 144B

  // Q fragments (16 rows x 64 d), kept in registers for the whole KV loop
  const u16* qrow = q + ((size_t)bh * S_ + qbase + lr) * HD_;
  FragU qf[2];
  #pragma unroll
  for (int dc = 0; dc < 2; ++dc) {
    qf[dc].d2[0] = *(const uint2*)(qrow + dc * 32 + g * 4);
    qf[dc].d2[1] = *(const uint2*)(qrow + dc * 32 + 16 + g * 4);
  }

  const u16* kbase = k + (size_t)bh * S_ * HD_;
  const u16* vbase = vt + (size_t)bh * HD_ * S_;

  const f32x4 zero = {0.f, 0.f, 0.f, 0.f};
  f32x4 accO[4] = {zero, zero, zero, zero};
  float m_[4] = {-3e38f, -3e38f, -3e38f, -3e38f};
  float l_[4] = {0.f, 0.f, 0.f, 0.f};

  for (int t0 = 0; t0 < S_; t0 += 64) {
    // ---- scores S[16 q][64 t] (q already carries 1/sqrt(d)) ----
    f32x4 sc[4] = {zero, zero, zero, zero};
    #pragma unroll
    for (int ct = 0; ct < 4; ++ct) {
      const u16* krow = kbase + (size_t)(t0 + ct * 16 + lr) * HD_;
      #pragma unroll
      for (int dc = 0; dc < 2; ++dc) {
        FragU kf;
        kf.d2[0] = *(const uint2*)(krow + dc * 32 + g * 4);
        kf.d2[1] = *(const uint2*)(krow + dc * 32 + 16 + g * 4);
        sc[ct] = __builtin_amdgcn_mfma_f32_16x16x32_bf16(qf[dc].v, kf.v, sc[ct], 0, 0, 0);
      }
    }
    // ---- online softmax (rows live on 16-lane groups) ----
    float mn[4], al[4], ps[4];
    #pragma unroll
    for (int r = 0; r < 4; ++r) {
      float mt_ = fmaxf(fmaxf(sc[0][r], sc[1][r]), fmaxf(sc[2][r], sc[3][r]));
      #pragma unroll
      for (int j = 1; j < 16; j <<= 1) mt_ = fmaxf(mt_, __shfl_xor(mt_, j));
      mn[r] = fmaxf(m_[r], mt_);
      al[r] = __expf(m_[r] - mn[r]);
      m_[r] = mn[r];
      ps[r] = 0.f;
    }
    #pragma unroll
    for (int ct = 0; ct < 4; ++ct)
      #pragma unroll
      for (int r = 0; r < 4; ++r) {
        float p = __expf(sc[ct][r] - mn[r]);
        sc[ct][r] = p;
        ps[r] += p;
      }
    #pragma unroll
    for (int r = 0; r < 4; ++r) {
      #pragma unroll
      for (int j = 1; j < 16; j <<= 1) ps[r] += __shfl_xor(ps[r], j);
      l_[r] = l_[r] * al[r] + ps[r];
    }
    #pragma unroll
    for (int dt = 0; dt < 4; ++dt)
      #pragma unroll
      for (int r = 0; r < 4; ++r) accO[dt][r] *= al[r];

    // ---- P -> LDS (bf16), re-read as MFMA A-fragments ----
    #pragma unroll
    for (int ct = 0; ct < 4; ++ct)
      #pragma unroll
      for (int r = 0; r < 4; ++r)
        Plds[w][g * 4 + r][ct * 16 + lr] = f2bf(sc[ct][r]);

    FragU pf[2];
    #pragma unroll
    for (int tc = 0; tc < 2; ++tc) {
      const u16* pr = &Plds[w][lr][tc * 32 + g * 4];
      pf[tc].d2[0] = *(const uint2*)pr;
      pf[tc].d2[1] = *(const uint2*)(pr + 16);
    }
    // ---- PV: accO[16 q][64 d] += P @ V  (V^T rows are d, contiguous in t) ----
    #pragma unroll
    for (int dt = 0; dt < 4; ++dt) {
      const u16* vrow = vbase + (size_t)(dt * 16 + lr) * S_ + t0;
      #pragma unroll
      for (int tc = 0; tc < 2; ++tc) {
        FragU vf;
        vf.d2[0] = *(const uint2*)(vrow + tc * 32 + g * 4);
        vf.d2[1] = *(const uint2*)(vrow + tc * 32 + 16 + g * 4);
        accO[dt] = __builtin_amdgcn_mfma_f32_16x16x32_bf16(pf[tc].v, vf.v, accO[dt], 0, 0, 0);
      }
    }
  }

  // epilogue: normalize by l, store to [B,S,H*64] f32
  const int b = bh >> 4, h = bh & (H_ - 1);
  #pragma unroll
  for (int r = 0; r < 4; ++r) {
    float inv = 1.0f / l_[r];
    int s = qbase + g * 4 + r;
    float* op = att + ((size_t)b * S_ + s) * D_ + h * HD_;
    #pragma unroll
    for (int dt = 0; dt < 4; ++dt) op[dt * 16 + lr] = accO[dt][r] * inv;
  }
}

// ---------------------------------------------------------------------------
// LayerNorm over last dim (1024): one block per row.
// ---------------------------------------------------------------------------
__global__ __launch_bounds__(256) void ln_kernel(
    const float* __restrict__ att, const float* __restrict__ gamma,
    const float* __restrict__ beta, float* __restrict__ out)
{
  const int row = blockIdx.x;
  const int tid = threadIdx.x;
  const float4 x = ((const float4*)(att + (size_t)row * D_))[tid];
  float s  = x.x + x.y + x.z + x.w;
  float sq = x.x * x.x + x.y * x.y + x.z * x.z + x.w * x.w;
  #pragma unroll
  for (int j = 1; j < 64; j <<= 1) { s += __shfl_xor(s, j); sq += __shfl_xor(sq, j); }
  __shared__ float ls[4], lq[4];
  const int w = tid >> 6;
  if ((tid & 63) == 0) { ls[w] = s; lq[w] = sq; }
  __syncthreads();
  if (tid == 0) {
    ls[0] = ls[0] + ls[1] + ls[2] + ls[3];
    lq[0] = lq[0] + lq[1] + lq[2] + lq[3];
  }
  __syncthreads();
  const float mean = ls[0] * (1.f / D_);
  const float var  = lq[0] * (1.f / D_) - mean * mean;
  const float rs = rsqrtf(var + 1e-5f);
  const float4 gv = ((const float4*)gamma)[tid];
  const float4 bv = ((const float4*)beta)[tid];
  float4 o;
  o.x = (x.x - mean) * rs * gv.x + bv.x;
  o.y = (x.y - mean) * rs * gv.y + bv.y;
  o.z = (x.z - mean) * rs * gv.z + bv.z;
  o.w = (x.w - mean) * rs * gv.w + bv.w;
  ((float4*)(out + (size_t)row * D_))[tid] = o;
}

extern "C" void kernel_launch(void* const* d_in, const int* in_sizes, int n_in,
                              void* d_out, int out_size, void* d_ws, size_t ws_size,
                              hipStream_t stream) {
  const float* queries = (const float*)d_in[0];
  const float* keys    = (const float*)d_in[1];
  const float* values  = (const float*)d_in[2];
  const float* Wq = (const float*)d_in[3];
  const float* bq = (const float*)d_in[4];
  const float* Wk = (const float*)d_in[5];
  const float* bk = (const float*)d_in[6];
  const float* Wv = (const float*)d_in[7];
  const float* bv = (const float*)d_in[8];
  const float* gamma = (const float*)d_in[9];
  const float* beta  = (const float*)d_in[10];
  float* out = (float*)d_out;

  const size_t PER = (size_t)B_ * H_ * S_ * HD_;   // 4,194,304 elements
  u16* q_ws  = (u16*)d_ws;
  u16* k_ws  = q_ws + PER;
  u16* vt_ws = k_ws + PER;
  float* att_ws = (float*)(vt_ws + PER);           // total ws use: 42 MB

  proj_kernel<<<dim3(32, 16, 3), 256, 0, stream>>>(
      queries, keys, values, Wq, Wk, Wv, bq, bk, bv, q_ws, k_ws, vt_ws);
  attn_kernel<<<dim3(32, 32), 256, 0, stream>>>(q_ws, k_ws, vt_ws, att_ws);
  ln_kernel<<<dim3(4096), 256, 0, stream>>>(att_ws, gamma, beta, out);
}

// Round 2
// 198.658 us; speedup vs baseline: 2.7543x; 2.7543x over previous
//
#include <hip/hip_runtime.h>

#define B_ 2
#define S_ 2048
#define D_ 1024
#define H_ 16
#define HD_ 64

typedef unsigned short u16;
typedef short bf16x8 __attribute__((ext_vector_type(8)));
typedef float f32x4 __attribute__((ext_vector_type(4)));

union FragU { bf16x8 v; u16 u[8]; uint2 d2[2]; };

__device__ __forceinline__ u16 f2bf(float f) {
  unsigned int x = __builtin_bit_cast(unsigned int, f);
  x += 0x7fffu + ((x >> 16) & 1u);   // round-to-nearest-even
  return (u16)(x >> 16);
}

// ---------------------------------------------------------------------------
// Projection: out[z] = X[z] @ W[z] + b[z]   (z: 0=q, 1=k, 2=v)
// q,k written [B,H,S,64] bf16 (q pre-scaled by 1/8); v written [B,H,64,S] bf16
// ---------------------------------------------------------------------------
__global__ __launch_bounds__(256) void proj_kernel(
    const float* __restrict__ Xq, const float* __restrict__ Xk, const float* __restrict__ Xv,
    const float* __restrict__ Wq, const float* __restrict__ Wk, const float* __restrict__ Wv,
    const float* __restrict__ bq, const float* __restrict__ bk, const float* __restrict__ bv,
    u16* __restrict__ qo, u16* __restrict__ ko, u16* __restrict__ vo)
{
  const int z = blockIdx.z;
  const float* X  = (z == 0) ? Xq : (z == 1) ? Xk : Xv;
  const float* W  = (z == 0) ? Wq : (z == 1) ? Wk : Wv;
  const float* Bb = (z == 0) ? bq : (z == 1) ? bk : bv;
  u16* out = (z == 0) ? qo : (z == 1) ? ko : vo;
  const float scale = (z == 0) ? 0.125f : 1.0f;

  const int h = blockIdx.y;
  const int bx = blockIdx.x;
  const int tid = threadIdx.x;
  const int l = tid & 63, w = tid >> 6;
  const int g = l >> 4, lr = l & 15;

  __shared__ u16 Asm[128][36];
  __shared__ u16 Wsm[64][36];

  const f32x4 zero = {0.f, 0.f, 0.f, 0.f};
  f32x4 acc[2][4];
  for (int mt = 0; mt < 2; ++mt)
    for (int nt = 0; nt < 4; ++nt) acc[mt][nt] = zero;

  for (int k0 = 0; k0 < D_; k0 += 32) {
    #pragma unroll
    for (int i = 0; i < 16; ++i) {
      int idx = tid + i * 256;
      int r = idx >> 5, kk = idx & 31;
      Asm[r][kk] = f2bf(X[(size_t)(bx * 128 + r) * D_ + k0 + kk]);
    }
    #pragma unroll
    for (int i = 0; i < 8; ++i) {
      int idx = tid + i * 256;
      int n = idx & 63, kk = idx >> 6;
      Wsm[n][kk] = f2bf(W[((size_t)h * D_ + k0 + kk) * HD_ + n]);
    }
    __syncthreads();

    FragU aF[2], bF[4];
    #pragma unroll
    for (int mt = 0; mt < 2; ++mt) {
      const u16* p = &Asm[w * 32 + mt * 16 + lr][g * 4];
      aF[mt].d2[0] = *(const uint2*)p;
      aF[mt].d2[1] = *(const uint2*)(p + 16);
    }
    #pragma unroll
    for (int nt = 0; nt < 4; ++nt) {
      const u16* p = &Wsm[nt * 16 + lr][g * 4];
      bF[nt].d2[0] = *(const uint2*)p;
      bF[nt].d2[1] = *(const uint2*)(p + 16);
    }
    #pragma unroll
    for (int mt = 0; mt < 2; ++mt)
      #pragma unroll
      for (int nt = 0; nt < 4; ++nt)
        acc[mt][nt] = __builtin_amdgcn_mfma_f32_16x16x32_bf16(aF[mt].v, bF[nt].v, acc[mt][nt], 0, 0, 0);
    __syncthreads();
  }

  #pragma unroll
  for (int nt = 0; nt < 4; ++nt) {
    int n = nt * 16 + lr;
    float bias = Bb[h * HD_ + n];
    #pragma unroll
    for (int mt = 0; mt < 2; ++mt) {
      #pragma unroll
      for (int r = 0; r < 4; ++r) {
        int R = bx * 128 + w * 32 + mt * 16 + g * 4 + r;
        int b = R >> 11, s = R & (S_ - 1);
        float val = (acc[mt][nt][r] + bias) * scale;
        if (z < 2)
          out[(((size_t)b * H_ + h) * S_ + s) * HD_ + n] = f2bf(val);
        else
          out[(((size_t)b * H_ + h) * HD_ + n) * S_ + s] = f2bf(val);
      }
    }
  }
}

// ---------------------------------------------------------------------------
// Flash attention, v2: LDS-staged K/V (shared by 4 waves, XOR-swizzled),
// reg-staged prefetch, swapped QK^T (per-lane q-row softmax, 2 shfls).
// ---------------------------------------------------------------------------
__global__ __launch_bounds__(256, 4) void attn_kernel(
    const u16* __restrict__ q, const u16* __restrict__ k,
    const u16* __restrict__ vt, float* __restrict__ att)
{
  // XCD swizzle: each XCD gets 4 bh values (2 MB K/V -> L2-resident)
  const int bid = blockIdx.x;
  const int xcd = bid & 7;
  const int j = bid >> 3;
  const int qt = j & 31;
  const int bh = ((j >> 5) << 3) | xcd;

  const int tid = threadIdx.x;
  const int l = tid & 63, w = tid >> 6;
  const int g = l >> 4, lr = l & 15;
  const int qbase = qt * 64 + w * 16;

  __shared__ u16 Ksm[64 * 64];      // [t][d], swizzled rows of 128B
  __shared__ u16 Vsm[64 * 64];      // [d][t], swizzled rows of 128B
  __shared__ u16 Plds[4][16][72];   // per-wave P tile [q][t], pad 72

  // Q fragments (16 rows x 64 d) in registers for the whole KV loop
  const u16* qrow = q + ((size_t)bh * S_ + qbase + lr) * HD_;
  FragU qf[2];
  #pragma unroll
  for (int dc = 0; dc < 2; ++dc) {
    qf[dc].d2[0] = *(const uint2*)(qrow + dc * 32 + g * 4);
    qf[dc].d2[1] = *(const uint2*)(qrow + dc * 32 + 16 + g * 4);
  }

  const char* kByte = (const char*)(k + (size_t)bh * S_ * HD_);
  const char* vByte = (const char*)(vt + (size_t)bh * HD_ * S_);

  // staging geometry: 2 chunks of 16B per thread, linear LDS dest,
  // pre-swizzled global source (rule 21 / m173)
  const int lo0 = tid * 16, lo1 = tid * 16 + 4096;
  const int r0 = lo0 >> 7, cb0 = lo0 & 127, s0 = cb0 ^ ((r0 & 7) << 4);
  const int r1 = lo1 >> 7, cb1 = lo1 & 127, s1 = cb1 ^ ((r1 & 7) << 4);

  uint4 kA, kB, vA, vB;
  // prologue: stage tile 0
  kA = *(const uint4*)(kByte + (size_t)r0 * 128 + s0);
  kB = *(const uint4*)(kByte + (size_t)r1 * 128 + s1);
  vA = *(const uint4*)(vByte + (size_t)r0 * S_ * 2 + s0);
  vB = *(const uint4*)(vByte + (size_t)r1 * S_ * 2 + s1);
  *(uint4*)((char*)Ksm + lo0) = kA;
  *(uint4*)((char*)Ksm + lo1) = kB;
  *(uint4*)((char*)Vsm + lo0) = vA;
  *(uint4*)((char*)Vsm + lo1) = vB;
  __syncthreads();

  const f32x4 zero = {0.f, 0.f, 0.f, 0.f};
  f32x4 accO[4] = {zero, zero, zero, zero};
  float m_ = -3e38f, l_ = 0.f;      // per-lane: q-row = lr (replicated over g)

#define KREAD(row, cbase) (*(const uint2*)((const char*)Ksm + (row) * 128 + ((cbase) ^ (((row) & 7) << 4))))
#define VREAD(row, cbase) (*(const uint2*)((const char*)Vsm + (row) * 128 + ((cbase) ^ (((row) & 7) << 4))))

  for (int t0 = 0; t0 < S_; t0 += 64) {
    const bool hasNext = (t0 + 64) < S_;
    if (hasNext) {   // prefetch next tile into regs (latency hides under compute)
      kA = *(const uint4*)(kByte + (size_t)(t0 + 64 + r0) * 128 + s0);
      kB = *(const uint4*)(kByte + (size_t)(t0 + 64 + r1) * 128 + s1);
      vA = *(const uint4*)(vByte + (size_t)r0 * S_ * 2 + (t0 + 64) * 2 + s0);
      vB = *(const uint4*)(vByte + (size_t)r1 * S_ * 2 + (t0 + 64) * 2 + s1);
    }

    // ---- scores S^T[64 t][16 q]: A=K, B=Q (swapped) ----
    f32x4 sc[4] = {zero, zero, zero, zero};
    #pragma unroll
    for (int ct = 0; ct < 4; ++ct) {
      const int trow = ct * 16 + lr;
      #pragma unroll
      for (int dc = 0; dc < 2; ++dc) {
        FragU kf;
        kf.d2[0] = KREAD(trow, dc * 64 + g * 8);
        kf.d2[1] = KREAD(trow, dc * 64 + g * 8 + 32);
        sc[ct] = __builtin_amdgcn_mfma_f32_16x16x32_bf16(kf.v, qf[dc].v, sc[ct], 0, 0, 0);
      }
    }
    // lane (g,lr) holds P[q=lr][t = ct*16 + 4g + r]

    // ---- online softmax: per-lane q-row, 2-shfl reductions ----
    float mloc = sc[0][0];
    #pragma unroll
    for (int ct = 0; ct < 4; ++ct)
      #pragma unroll
      for (int r = 0; r < 4; ++r) mloc = fmaxf(mloc, sc[ct][r]);
    mloc = fmaxf(mloc, __shfl_xor(mloc, 16));
    mloc = fmaxf(mloc, __shfl_xor(mloc, 32));
    const float mn = fmaxf(m_, mloc);
    const float al = __expf(m_ - mn);
    m_ = mn;
    float ps = 0.f;
    #pragma unroll
    for (int ct = 0; ct < 4; ++ct)
      #pragma unroll
      for (int r = 0; r < 4; ++r) {
        float p = __expf(sc[ct][r] - mn);
        sc[ct][r] = p;
        ps += p;
      }
    ps += __shfl_xor(ps, 16);
    ps += __shfl_xor(ps, 32);
    l_ = l_ * al + ps;

    // ---- P -> LDS (packed 8B writes), re-read as PV A-fragments ----
    #pragma unroll
    for (int ct = 0; ct < 4; ++ct) {
      union { u16 u[4]; uint2 d; } pk;
      #pragma unroll
      for (int r = 0; r < 4; ++r) pk.u[r] = f2bf(sc[ct][r]);
      *(uint2*)(&Plds[w][lr][ct * 16 + g * 4]) = pk.d;
    }
    // rescale accO rows (q = 4g + r) by al broadcast from lane 4g+r
    float alr[4];
    #pragma unroll
    for (int r = 0; r < 4; ++r) alr[r] = __shfl(al, g * 4 + r);
    #pragma unroll
    for (int dt = 0; dt < 4; ++dt)
      #pragma unroll
      for (int r = 0; r < 4; ++r) accO[dt][r] *= alr[r];

    FragU pf[2];
    #pragma unroll
    for (int tc = 0; tc < 2; ++tc) {
      const u16* pr = &Plds[w][lr][tc * 32 + g * 4];
      pf[tc].d2[0] = *(const uint2*)pr;
      pf[tc].d2[1] = *(const uint2*)(pr + 16);
    }

    // ---- PV: accO[16 q][64 d] += P @ V ----
    #pragma unroll
    for (int dt = 0; dt < 4; ++dt) {
      const int drow = dt * 16 + lr;
      #pragma unroll
      for (int tc = 0; tc < 2; ++tc) {
        FragU vf;
        vf.d2[0] = VREAD(drow, tc * 64 + g * 8);
        vf.d2[1] = VREAD(drow, tc * 64 + g * 8 + 32);
        accO[dt] = __builtin_amdgcn_mfma_f32_16x16x32_bf16(pf[tc].v, vf.v, accO[dt], 0, 0, 0);
      }
    }

    __syncthreads();             // all waves done reading current K/V tile
    if (hasNext) {
      *(uint4*)((char*)Ksm + lo0) = kA;
      *(uint4*)((char*)Ksm + lo1) = kB;
      *(uint4*)((char*)Vsm + lo0) = vA;
      *(uint4*)((char*)Vsm + lo1) = vB;
    }
    __syncthreads();             // staged writes visible
  }

  // epilogue: normalize (inv-l broadcast lr-space -> (g,r)-space), store
  const float inv = 1.0f / l_;
  const int b = bh >> 4, h = bh & (H_ - 1);
  #pragma unroll
  for (int r = 0; r < 4; ++r) {
    const float ivr = __shfl(inv, g * 4 + r);
    const int s = qbase + g * 4 + r;
    float* op = att + ((size_t)b * S_ + s) * D_ + h * HD_;
    #pragma unroll
    for (int dt = 0; dt < 4; ++dt) op[dt * 16 + lr] = accO[dt][r] * ivr;
  }
#undef KREAD
#undef VREAD
}

// ---------------------------------------------------------------------------
// LayerNorm over last dim (1024): one block per row.
// ---------------------------------------------------------------------------
__global__ __launch_bounds__(256) void ln_kernel(
    const float* __restrict__ att, const float* __restrict__ gamma,
    const float* __restrict__ beta, float* __restrict__ out)
{
  const int row = blockIdx.x;
  const int tid = threadIdx.x;
  const float4 x = ((const float4*)(att + (size_t)row * D_))[tid];
  float s  = x.x + x.y + x.z + x.w;
  float sq = x.x * x.x + x.y * x.y + x.z * x.z + x.w * x.w;
  #pragma unroll
  for (int j = 1; j < 64; j <<= 1) { s += __shfl_xor(s, j); sq += __shfl_xor(sq, j); }
  __shared__ float ls[4], lq[4];
  const int w = tid >> 6;
  if ((tid & 63) == 0) { ls[w] = s; lq[w] = sq; }
  __syncthreads();
  if (tid == 0) {
    ls[0] = ls[0] + ls[1] + ls[2] + ls[3];
    lq[0] = lq[0] + lq[1] + lq[2] + lq[3];
  }
  __syncthreads();
  const float mean = ls[0] * (1.f / D_);
  const float var  = lq[0] * (1.f / D_) - mean * mean;
  const float rs = rsqrtf(var + 1e-5f);
  const float4 gv = ((const float4*)gamma)[tid];
  const float4 bv = ((const float4*)beta)[tid];
  float4 o;
  o.x = (x.x - mean) * rs * gv.x + bv.x;
  o.y = (x.y - mean) * rs * gv.y + bv.y;
  o.z = (x.z - mean) * rs * gv.z + bv.z;
  o.w = (x.w - mean) * rs * gv.w + bv.w;
  ((float4*)(out + (size_t)row * D_))[tid] = o;
}

extern "C" void kernel_launch(void* const* d_in, const int* in_sizes, int n_in,
                              void* d_out, int out_size, void* d_ws, size_t ws_size,
                              hipStream_t stream) {
  const float* queries = (const float*)d_in[0];
  const float* keys    = (const float*)d_in[1];
  const float* values  = (const float*)d_in[2];
  const float* Wq = (const float*)d_in[3];
  const float* bq = (const float*)d_in[4];
  const float* Wk = (const float*)d_in[5];
  const float* bk = (const float*)d_in[6];
  const float* Wv = (const float*)d_in[7];
  const float* bv = (const float*)d_in[8];
  const float* gamma = (const float*)d_in[9];
  const float* beta  = (const float*)d_in[10];
  float* out = (float*)d_out;

  const size_t PER = (size_t)B_ * H_ * S_ * HD_;
  u16* q_ws  = (u16*)d_ws;
  u16* k_ws  = q_ws + PER;
  u16* vt_ws = k_ws + PER;
  float* att_ws = (float*)(vt_ws + PER);

  proj_kernel<<<dim3(32, 16, 3), 256, 0, stream>>>(
      queries, keys, values, Wq, Wk, Wv, bq, bk, bv, q_ws, k_ws, vt_ws);
  attn_kernel<<<dim3(1024), 256, 0, stream>>>(q_ws, k_ws, vt_ws, att_ws);
  ln_kernel<<<dim3(4096), 256, 0, stream>>>(att_ws, gamma, beta, out);
}